// Round 2
// baseline (495.234 us; speedup 1.0000x reference)
//
#include <hip/hip_runtime.h>
#include <hip/hip_cooperative_groups.h>
#include <math.h>

namespace cg = cooperative_groups;

#define N_NODES 10000
#define N_EDGES 320000
#define IN_DIM  128
#define HID     256
#define CAP     128      // fixed bucket capacity; Poisson(32) => overflow prob ~0
#define NBLK    512      // cooperative grid: 2 blocks/CU, validated by runtime

typedef __attribute__((ext_vector_type(8))) short frag_ab;
typedef __attribute__((ext_vector_type(4))) float frag_cd;

// ---------------- workspace layout (bytes) ----------------
// yb     : N_NODES*64 u32       @ 0          (aggregated y, packed bf16x2)
// G      : 256*1024 f32         @ 2,560,000
// Wev    : 256*256 f32          @ 3,608,576
// WcT    : 256*64 u32           @ 3,870,720  (Wc^T, packed bf16x2 [n][k])
// bc     : 256 f32              @ 3,936,256
// rs     : N_NODES f32          @ 3,937,280
// xb     : N_NODES*64 u32       @ 3,977,280  (x, packed bf16x2)
// cursor : N_NODES i32          @ 6,537,280
// bucket : N_NODES*CAP i32      @ 6,617,280

__device__ __forceinline__ unsigned bf16rne(float f) {
    union { float f; unsigned u; } c; c.f = f;
    return (c.u + 0x7FFFu + ((c.u >> 16) & 1u)) >> 16;
}
__device__ __forceinline__ float sig_f(float x)  { return 1.f / (1.f + __expf(-x)); }
__device__ __forceinline__ float tanh_f(float x) { return 1.f - 2.f / (1.f + __expf(2.f * x)); }

__global__ __launch_bounds__(256, 2)
void k_fused(const float* __restrict__ x, const int* __restrict__ ei,
             const float* __restrict__ Wp, const float* __restrict__ bp,
             const float* __restrict__ wih, const float* __restrict__ whh,
             const float* __restrict__ b_ih, const float* __restrict__ b_hh,
             const float* __restrict__ iw, const float* __restrict__ b_gcn,
             float* __restrict__ out,
             unsigned* __restrict__ yb, float* __restrict__ G,
             float* __restrict__ Wev, unsigned* __restrict__ wct,
             float* __restrict__ bc, float* __restrict__ rs,
             unsigned* __restrict__ xb, int* __restrict__ cursor,
             int* __restrict__ bucket) {
    __shared__ float smem[6144];     // 24 KB: gates staging (P0) / Wc arows (P2)
    cg::grid_group grid = cg::this_grid();
    const int bid = blockIdx.x;
    const int t = threadIdx.x;

    // ========== P0: gates GEMM (blocks 384..511) | x->bf16 (blocks 0..383) ==========
    if (bid >= 384) {
        // G[256,1024] = iw[256,256] @ (W_ih + W_hh)^T ; 32m x 64n tiles, 2x4 micro
        int gb = bid - 384;
        int m0 = (gb & 7) * 32, n0 = (gb >> 3) * 64;
        float (*aT)[32] = (float(*)[32])smem;             // aT[kk][m]  [64][32]
        float (*bS)[64] = (float(*)[64])(smem + 2048);    // bS[kk][n]  [64][64]
        int tm = t & 15, tn = t >> 4;
        float acc[2][4] = {};
        for (int kt = 0; kt < 4; ++kt) {
            int k0 = kt * 64;
            {   // stage A: 32 rows x 16 float4
                int row = t >> 3;
                #pragma unroll
                for (int r = 0; r < 2; ++r) {
                    int kq = 2 * (t & 7) + r;
                    float4 av = *(const float4*)&iw[(m0 + row) * HID + k0 + 4 * kq];
                    aT[4 * kq + 0][row] = av.x; aT[4 * kq + 1][row] = av.y;
                    aT[4 * kq + 2][row] = av.z; aT[4 * kq + 3][row] = av.w;
                }
            }
            {   // stage B: 64 rows x 16 float4 (wih+whh)
                int row = t >> 2;
                #pragma unroll
                for (int r = 0; r < 4; ++r) {
                    int kq = 4 * (t & 3) + r;
                    float4 b1 = *(const float4*)&wih[(n0 + row) * HID + k0 + 4 * kq];
                    float4 b2 = *(const float4*)&whh[(n0 + row) * HID + k0 + 4 * kq];
                    bS[4 * kq + 0][row] = b1.x + b2.x; bS[4 * kq + 1][row] = b1.y + b2.y;
                    bS[4 * kq + 2][row] = b1.z + b2.z; bS[4 * kq + 3][row] = b1.w + b2.w;
                }
            }
            __syncthreads();
            #pragma unroll 8
            for (int kk = 0; kk < 64; ++kk) {
                float2 a2 = *(const float2*)&aT[kk][2 * tm];
                float4 b4 = *(const float4*)&bS[kk][4 * tn];
                float a[2] = {a2.x, a2.y};
                float b[4] = {b4.x, b4.y, b4.z, b4.w};
                #pragma unroll
                for (int i = 0; i < 2; ++i)
                    #pragma unroll
                    for (int j = 0; j < 4; ++j)
                        acc[i][j] = fmaf(a[i], b[j], acc[i][j]);
            }
            __syncthreads();
        }
        #pragma unroll
        for (int i = 0; i < 2; ++i) {
            float4 o = make_float4(acc[i][0], acc[i][1], acc[i][2], acc[i][3]);
            *(float4*)&G[(m0 + 2 * tm + i) * 1024 + n0 + 4 * tn] = o;
        }
    } else {
        // x -> packed bf16x2 (640,000 u32), strided over 384 blocks
        const float2* x2 = (const float2*)x;
        for (int idx = bid * 256 + t; idx < N_NODES * 64; idx += 384 * 256) {
            float2 v = x2[idx];
            xb[idx] = bf16rne(v.x) | (bf16rne(v.y) << 16);
        }
    }
    __threadfence();
    grid.sync();

    // ========== P1: LSTM -> Wev (blocks 0..255) | bucket fill (blocks 256..511) ==========
    if (bid < 256) {
        int r = bid, j = t;
        float gi = G[r * 1024 + 0   + j] + b_ih[0   + j] + b_hh[0   + j];
        float gf = G[r * 1024 + 256 + j] + b_ih[256 + j] + b_hh[256 + j];
        float gg = G[r * 1024 + 512 + j] + b_ih[512 + j] + b_hh[512 + j];
        float go = G[r * 1024 + 768 + j] + b_ih[768 + j] + b_hh[768 + j];
        float c  = sig_f(gf) * iw[r * HID + j] + sig_f(gi) * tanh_f(gg);
        Wev[r * HID + j] = sig_f(go) * tanh_f(c);
    } else {
        int gid = (bid - 256) * 256 + t;          // 0..65535
        for (int u = gid; u < N_EDGES / 4; u += 256 * 256) {
            int4 s4 = *(const int4*)&ei[u * 4];
            int4 d4 = *(const int4*)&ei[N_EDGES + u * 4];
            int p0 = atomicAdd(&cursor[d4.x], 1);
            if (p0 < CAP) bucket[d4.x * CAP + p0] = s4.x;
            int p1 = atomicAdd(&cursor[d4.y], 1);
            if (p1 < CAP) bucket[d4.y * CAP + p1] = s4.y;
            int p2 = atomicAdd(&cursor[d4.z], 1);
            if (p2 < CAP) bucket[d4.z * CAP + p2] = s4.z;
            int p3 = atomicAdd(&cursor[d4.w], 1);
            if (p3 < CAP) bucket[d4.w * CAP + p3] = s4.w;
        }
    }
    __threadfence();
    grid.sync();

    // ========== P2: Wc GEMM -> wct/bc (blocks 0..16) | aggregation (blocks 17..511) ==========
    if (bid < 17) {
        if (bid < 16) {
            // 8 rows of Wc^T per block: coalesced 16B bf16x8 writes, 8 FMA per Wev load
            int a0 = bid * 8;
            float (*ar)[HID] = (float(*)[HID])smem;   // [8][256] = 8 KB
            #pragma unroll
            for (int r = 0; r < 8; ++r) ar[r][t] = Wp[(a0 + r) * HID + t];
            __syncthreads();
            int j = t;
            float acc[8] = {};
            #pragma unroll 4
            for (int k = 0; k < HID; ++k) {
                float w = Wev[k * HID + j];
                #pragma unroll
                for (int r = 0; r < 8; ++r) acc[r] = fmaf(ar[r][k], w, acc[r]);
            }
            uint4 pv;
            pv.x = bf16rne(acc[0]) | (bf16rne(acc[1]) << 16);
            pv.y = bf16rne(acc[2]) | (bf16rne(acc[3]) << 16);
            pv.z = bf16rne(acc[4]) | (bf16rne(acc[5]) << 16);
            pv.w = bf16rne(acc[6]) | (bf16rne(acc[7]) << 16);
            *(uint4*)((unsigned short*)wct + j * IN_DIM + a0) = pv;
        } else {
            // bias row: bc[j] = sum_k bp[k] * Wev[k][j]
            smem[t] = bp[t];
            __syncthreads();
            float acc = 0.f;
            #pragma unroll 4
            for (int k = 0; k < HID; ++k)
                acc = fmaf(smem[k], Wev[k * HID + t], acc);
            bc[t] = acc;
        }
    } else {
        // aggregation; dinv computed on-the-fly from cursor
        int wv = t >> 6, lane = t & 63;
        for (int v = (bid - 17) * 4 + wv; v < N_NODES; v += 495 * 4) {
            int cntv = cursor[v];
            float dv = rsqrtf((float)(cntv + 1));
            int cnt = cntv > CAP ? CAP : cntv;
            unsigned self = xb[v * 64 + lane];
            union { unsigned u; float f; } c0, c1;
            c0.u = self << 16; c1.u = self & 0xFFFF0000u;
            float acc0 = dv * c0.f, acc1 = dv * c1.f;
            float wsum = dv;
            const int4* bkt4 = (const int4*)&bucket[v * CAP];
            int j = 0;
            for (; j + 4 <= cnt; j += 4) {
                int4 s = bkt4[j >> 2];
                float w0 = rsqrtf((float)(cursor[s.x] + 1));
                float w1 = rsqrtf((float)(cursor[s.y] + 1));
                float w2 = rsqrtf((float)(cursor[s.z] + 1));
                float w3 = rsqrtf((float)(cursor[s.w] + 1));
                unsigned r0 = xb[s.x * 64 + lane];
                unsigned r1 = xb[s.y * 64 + lane];
                unsigned r2 = xb[s.z * 64 + lane];
                unsigned r3 = xb[s.w * 64 + lane];
                union { unsigned u; float f; } a0, a1;
                a0.u = r0 << 16; a1.u = r0 & 0xFFFF0000u;
                acc0 = fmaf(w0, a0.f, acc0); acc1 = fmaf(w0, a1.f, acc1);
                a0.u = r1 << 16; a1.u = r1 & 0xFFFF0000u;
                acc0 = fmaf(w1, a0.f, acc0); acc1 = fmaf(w1, a1.f, acc1);
                a0.u = r2 << 16; a1.u = r2 & 0xFFFF0000u;
                acc0 = fmaf(w2, a0.f, acc0); acc1 = fmaf(w2, a1.f, acc1);
                a0.u = r3 << 16; a1.u = r3 & 0xFFFF0000u;
                acc0 = fmaf(w3, a0.f, acc0); acc1 = fmaf(w3, a1.f, acc1);
                wsum += w0 + w1 + w2 + w3;
            }
            for (; j < cnt; ++j) {
                int s = ((const int*)bkt4)[j];
                float w = rsqrtf((float)(cursor[s] + 1));
                unsigned r = xb[s * 64 + lane];
                union { unsigned u; float f; } a0, a1;
                a0.u = r << 16; a1.u = r & 0xFFFF0000u;
                acc0 = fmaf(w, a0.f, acc0); acc1 = fmaf(w, a1.f, acc1);
                wsum += w;
            }
            yb[v * 64 + lane] = bf16rne(dv * acc0) | (bf16rne(dv * acc1) << 16);
            if (lane == 0) rs[v] = dv * wsum;
        }
    }
    __threadfence();
    grid.sync();

    // ========== P3: out[10000,256] = yb @ WcT^T + rs*bc + b_gcn (bf16 MFMA) ==========
    // 625 tiles of 16 rows, grid-strided; wave w covers n-tiles w,w+4,w+8,w+12
    {
        int w = t >> 6, lane = t & 63;
        int q = lane >> 4, ln = lane & 15;
        const int4* yb4  = (const int4*)yb;
        const int4* wct4 = (const int4*)wct;
        for (int tile = bid; tile < 625; tile += NBLK) {
            int m0 = tile * 16;
            union { int4 v; frag_ab f; } a[4];
            #pragma unroll
            for (int kc = 0; kc < 4; ++kc)
                a[kc].v = yb4[(m0 + ln) * 16 + kc * 4 + q];
            float rsv[4];
            #pragma unroll
            for (int r = 0; r < 4; ++r) rsv[r] = rs[m0 + q * 4 + r];
            #pragma unroll
            for (int i = 0; i < 4; ++i) {
                int n0 = (w + 4 * i) * 16;
                union { int4 v; frag_ab f; } b[4];
                #pragma unroll
                for (int kc = 0; kc < 4; ++kc)
                    b[kc].v = wct4[(n0 + ln) * 16 + kc * 4 + q];
                frag_cd acc = {0.f, 0.f, 0.f, 0.f};
                #pragma unroll
                for (int kc = 0; kc < 4; ++kc)
                    acc = __builtin_amdgcn_mfma_f32_16x16x32_bf16(a[kc].f, b[kc].f, acc, 0, 0, 0);
                int n = n0 + ln;
                float bcv = bc[n], bgv = b_gcn[n];
                #pragma unroll
                for (int r = 0; r < 4; ++r) {
                    int m = m0 + q * 4 + r;
                    out[m * HID + n] = acc[r] + rsv[r] * bcv + bgv;
                }
            }
        }
    }
}

extern "C" void kernel_launch(void* const* d_in, const int* in_sizes, int n_in,
                              void* d_out, int out_size, void* d_ws, size_t ws_size,
                              hipStream_t stream) {
    const float* x     = (const float*)d_in[0];
    const int*   ei    = (const int*)d_in[1];
    const float* Wp    = (const float*)d_in[2];
    const float* bp    = (const float*)d_in[3];
    const float* W_ih  = (const float*)d_in[4];
    const float* W_hh  = (const float*)d_in[5];
    const float* b_ih  = (const float*)d_in[6];
    const float* b_hh  = (const float*)d_in[7];
    const float* iw    = (const float*)d_in[8];
    const float* b_gcn = (const float*)d_in[9];
    float* out = (float*)d_out;

    char* ws = (char*)d_ws;
    unsigned* yb     = (unsigned*)(ws + 0);
    float*    G      = (float*)   (ws + 2560000);
    float*    Wev    = (float*)   (ws + 3608576);
    unsigned* wct    = (unsigned*)(ws + 3870720);
    float*    bc     = (float*)   (ws + 3936256);
    float*    rs     = (float*)   (ws + 3937280);
    unsigned* xb     = (unsigned*)(ws + 3977280);
    int*      cursor = (int*)     (ws + 6537280);
    int*      bucket = (int*)     (ws + 6617280);

    hipMemsetAsync(cursor, 0, N_NODES * sizeof(int), stream);

    void* args[] = {
        (void*)&x, (void*)&ei, (void*)&Wp, (void*)&bp, (void*)&W_ih, (void*)&W_hh,
        (void*)&b_ih, (void*)&b_hh, (void*)&iw, (void*)&b_gcn, (void*)&out,
        (void*)&yb, (void*)&G, (void*)&Wev, (void*)&wct, (void*)&bc, (void*)&rs,
        (void*)&xb, (void*)&cursor, (void*)&bucket
    };
    hipLaunchCooperativeKernel((const void*)k_fused, dim3(NBLK), dim3(256),
                               args, 0, stream);
}